// Round 13
// baseline (284.193 us; speedup 1.0000x reference)
//
#include <hip/hip_runtime.h>
#include <hip/hip_bf16.h>
#include <stdint.h>

// LimitRegressor = relu(x@W1+b1)@W2+b2 followed by a fixed-point iteration
// whose unique fixed point is y*=out (tanh contraction; global early-exit at
// eps=1e-6 fires at k~13 with residual < 3e-7 << the 6.09e-2 threshold).
// So we emit out directly: two bf16 MFMA GEMMs.
//
// Both GEMMs: m201-style 8-phase schedule. 256x256 tile, BK=64, 8 waves
// (2Mx4N), mfma 16x16x32. LDS = 4 x 32KB tile buffers (A/B x parity), each
// split into two consumption-aligned 16KB halves:
//   A_LO = rows read by afl (global chunks 0,2), A_HI = afh (chunks 1,3),
//   B_01 = rows read by b01 (global rows with (r>>5)&1==0, permuted
//          contiguous), B_23 = b23 rows.
// Per phase: {ds-reads (12/4/8/0 b128) ; stage 1 half (2 gload_lds) ; BAR ;
// lgkm0 ; setprio(1) 16 MFMA setprio(0) ; BAR}, vmcnt(6) ONLY at phases 4/8
// (once per K-tile; 3 halves stay in flight; stage->certify = 3-7 phases).
// Stage targets rotate half-granularly: each overwrite is >=1 phase after
// that half's last read (audited). Chunk-XOR swizzle as R6 (0 conflicts).

#define DEV __device__ __forceinline__

typedef short bf16x8 __attribute__((ext_vector_type(8)));
typedef float f32x4 __attribute__((ext_vector_type(4)));

typedef __attribute__((address_space(1))) const unsigned char* gptr1_t;
typedef __attribute__((address_space(3))) unsigned char* lptr3_t;

DEV void async_copy16(const void* g, void* l) {
  __builtin_amdgcn_global_load_lds((gptr1_t)g, (lptr3_t)l, 16, 0, 0);
}

DEV unsigned short f2bf(float f) {
  union { float f; unsigned u; } v; v.f = f;
  unsigned u = v.u + 0x7FFFu + ((v.u >> 16) & 1u);  // RNE
  return (unsigned short)(u >> 16);
}

#define BAR()   __builtin_amdgcn_s_barrier()
#define LGKM0() asm volatile("s_waitcnt lgkmcnt(0)" ::: "memory")
#define VMW(n)  asm volatile("s_waitcnt vmcnt(" #n ")" ::: "memory")

// ---------------- prep kernels ----------------

__global__ void cvt_f32_bf16(const float4* __restrict__ in,
                             ushort4* __restrict__ out, int n4) {
  int i = blockIdx.x * blockDim.x + threadIdx.x;
  if (i >= n4) return;
  float4 v = in[i];
  ushort4 o;
  o.x = f2bf(v.x); o.y = f2bf(v.y); o.z = f2bf(v.z); o.w = f2bf(v.w);
  out[i] = o;
}

// f32 [R][C] row-major  ->  bf16 [C][R] row-major (W -> W^T as bf16)
__global__ void transpose_f32_bf16(const float* __restrict__ in,
                                   unsigned short* __restrict__ out,
                                   int R, int C) {
  __shared__ float tile[32][33];
  int c0 = blockIdx.x * 32, r0 = blockIdx.y * 32;
  int tx = threadIdx.x, ty = threadIdx.y;  // block (32, 8)
#pragma unroll
  for (int i = 0; i < 32; i += 8)
    tile[ty + i][tx] = in[(long)(r0 + ty + i) * C + (c0 + tx)];
  __syncthreads();
#pragma unroll
  for (int i = 0; i < 32; i += 8)
    out[(long)(c0 + ty + i) * R + (r0 + tx)] = f2bf(tile[tx][ty + i]);
}

// ---------------- 8-phase GEMM ----------------

#define RD_AFL(dst, bufA)                                                     \
  _Pragma("unroll") for (int m_ = 0; m_ < 4; ++m_)                            \
  _Pragma("unroll") for (int k_ = 0; k_ < 2; ++k_)                            \
    dst[m_][k_] = *(const bf16x8*)((bufA) + (wr * 64 + m_ * 16 + lr) * 128 +  \
                                   (c0 ^ (k_ << 6)));
#define RD_AFH(dst, bufA)                                                     \
  _Pragma("unroll") for (int m_ = 0; m_ < 4; ++m_)                            \
  _Pragma("unroll") for (int k_ = 0; k_ < 2; ++k_)                            \
    dst[m_][k_] = *(const bf16x8*)((bufA) + 16384 +                           \
                                   (wr * 64 + m_ * 16 + lr) * 128 +           \
                                   (c0 ^ (k_ << 6)));
#define RD_B01(dst, bufB)                                                     \
  _Pragma("unroll") for (int n_ = 0; n_ < 2; ++n_)                            \
  _Pragma("unroll") for (int k_ = 0; k_ < 2; ++k_)                            \
    dst[n_][k_] = *(const bf16x8*)((bufB) + (wc * 32 + n_ * 16 + lr) * 128 +  \
                                   (c0 ^ (k_ << 6)));
#define RD_B23(dst, bufB)                                                     \
  _Pragma("unroll") for (int n_ = 0; n_ < 2; ++n_)                            \
  _Pragma("unroll") for (int k_ = 0; k_ < 2; ++k_)                            \
    dst[n_][k_] = *(const bf16x8*)((bufB) + 16384 +                           \
                                   (wc * 32 + n_ * 16 + lr) * 128 +           \
                                   (c0 ^ (k_ << 6)));

#define QUAD(MB, NB, AF, BF)                                                \
  do {                                                                      \
    __builtin_amdgcn_s_setprio(1);                                          \
    _Pragma("unroll") for (int m_ = 0; m_ < 4; ++m_)                        \
    _Pragma("unroll") for (int n_ = 0; n_ < 2; ++n_) {                      \
      acc[(MB) + m_][(NB) + n_] = __builtin_amdgcn_mfma_f32_16x16x32_bf16(  \
          AF[m_][0], BF[n_][0], acc[(MB) + m_][(NB) + n_], 0, 0, 0);        \
      acc[(MB) + m_][(NB) + n_] = __builtin_amdgcn_mfma_f32_16x16x32_bf16(  \
          AF[m_][1], BF[n_][1], acc[(MB) + m_][(NB) + n_], 0, 0, 0);        \
    }                                                                       \
    __builtin_amdgcn_s_setprio(0);                                          \
  } while (0)

// stage macros: one half-tile = 2 x async_copy16. bufw = buf + wave*1024.
#define SA_LO(bufw, koff) { async_copy16(gAlo0 + (koff), (bufw));            \
                            async_copy16(gAlo1 + (koff), (bufw) + 8192); }
#define SA_HI(bufw, koff) { async_copy16(gAhi0 + (koff), (bufw) + 16384);    \
                            async_copy16(gAhi1 + (koff), (bufw) + 24576); }
#define SB_01(bufw, koff) { async_copy16(gB010 + (koff), (bufw));            \
                            async_copy16(gB011 + (koff), (bufw) + 8192); }
#define SB_23(bufw, koff) { async_copy16(gB230 + (koff), (bufw) + 16384);    \
                            async_copy16(gB231 + (koff), (bufw) + 24576); }

template <bool RELU_BF16>
__global__ __launch_bounds__(512, 2)
void gemm8p(const unsigned short* __restrict__ A,   // bf16 [M][K]
            const unsigned short* __restrict__ BT,  // bf16 [N][K]
            const float* __restrict__ bias,         // [N]
            void* __restrict__ Cout,                // bf16 or f32 [M][N]
            int M, int N, int K, int nbn_shift) {
  extern __shared__ char lds[];
  char* Ap = lds;             // A buf parity 0: [A_LO 16K][A_HI 16K]
  char* Aq = lds + 32768;     // A buf parity 1
  char* Bp = lds + 65536;     // B buf parity 0: [B_01 16K][B_23 16K]
  char* Bq = lds + 98304;     // B buf parity 1

  const int tid = threadIdx.x;
  const int wave = tid >> 6, lane = tid & 63;
  const int wr = wave >> 2, wc = wave & 3;  // 2x4 waves, each 128x64 out

  char* Apw = Ap + wave * 1024;
  char* Aqw = Aq + wave * 1024;
  char* Bpw = Bp + wave * 1024;
  char* Bqw = Bq + wave * 1024;

  // T1: XCD-aware block swizzle (grids here are multiples of 8)
  const int nwg = gridDim.x;
  const int wg = blockIdx.x;
  const int swz = (wg & 7) * (nwg >> 3) + (wg >> 3);
  const int bm = swz >> nbn_shift;
  const int bn = swz & ((1 << nbn_shift) - 1);
  const int m0 = bm << 8, n0 = bn << 8;

  // staging sources (pre-swizzled k, both-sides rule). rho = row-in-instr.
  const int rho = tid >> 3;
  const int sk = ((tid & 7) ^ (rho & 7)) << 3;
  // A halves: A_LO instr j covers global rows j*128 + rho; A_HI +64.
  const unsigned short* gAlo0 = A + (size_t)(m0 + rho) * K + sk;
  const unsigned short* gAlo1 = A + (size_t)(m0 + 128 + rho) * K + sk;
  const unsigned short* gAhi0 = gAlo0 + (size_t)64 * K;
  const unsigned short* gAhi1 = gAlo1 + (size_t)64 * K;
  // B halves: B_01 instr j covers global rows (j*2 + (rho>>5))*64 + (rho&31)
  const int bgr = ((rho >> 5) << 6) + (rho & 31);
  const unsigned short* gB010 = BT + (size_t)(n0 + bgr) * K + sk;
  const unsigned short* gB011 = BT + (size_t)(n0 + 128 + bgr) * K + sk;
  const unsigned short* gB230 = gB010 + (size_t)32 * K;
  const unsigned short* gB231 = gB011 + (size_t)32 * K;

  // read constants
  const int lr = lane & 15, lg = lane >> 4;
  const int c0 = ((lg ^ (lr & 7)) << 4);

  f32x4 acc[8][4] = {};
  bf16x8 af[4][2], b01[2][2], b23[2][2];

  // ---- prologue: tile0 (4 halves) + tile1 {A_LO,B_01,B_23}; VMW(6) ----
  SA_LO(Apw, 0); SA_HI(Apw, 0); SB_01(Bpw, 0); SB_23(Bpw, 0);
  SA_LO(Aqw, 64); SB_01(Bqw, 64); SB_23(Bqw, 64);
  VMW(6);   // certifies tile 0; tile1's 3 halves stay in flight
  BAR();

  const int NT = K >> 6;  // even, >= 4

  for (int it = 0; it < (NT - 2) / 2; ++it) {
    const int t = 2 * it;
    const int k1 = (t + 1) << 6, k2 = (t + 2) << 6, k3 = (t + 3) << 6;
    // P1: rd afl(p), b01(p); stage A_HI(t+1)
    RD_AFL(af, Ap); RD_B01(b01, Bp); SA_HI(Aqw, k1);
    BAR(); LGKM0(); QUAD(0, 0, af, b01); BAR();
    // P2: rd b23(p); stage A_LO(t+2)  [Ap.A_LO freed by P1]
    RD_B23(b23, Bp); SA_LO(Apw, k2);
    BAR(); LGKM0(); QUAD(0, 2, af, b23); BAR();
    // P3: rd afh(p); stage B_01(t+2)  [Bp.B_01 freed by P1]
    RD_AFH(af, Ap); SB_01(Bpw, k2);
    BAR(); LGKM0(); QUAD(4, 2, af, b23); BAR();
    // P4: stage B_23(t+2) [freed by P2]; certify tile t+1 (VMW(6))
    SB_23(Bpw, k2);
    BAR(); QUAD(4, 0, af, b01); VMW(6); BAR();
    // P5: rd afl(q), b01(q); stage A_HI(t+2) [Ap.A_HI freed by P3]
    RD_AFL(af, Aq); RD_B01(b01, Bq); SA_HI(Apw, k2);
    BAR(); LGKM0(); QUAD(0, 0, af, b01); BAR();
    // P6: rd b23(q); stage A_LO(t+3) [Aq.A_LO freed by P5]
    RD_B23(b23, Bq); SA_LO(Aqw, k3);
    BAR(); LGKM0(); QUAD(0, 2, af, b23); BAR();
    // P7: rd afh(q); stage B_01(t+3) [freed by P5]
    RD_AFH(af, Aq); SB_01(Bqw, k3);
    BAR(); LGKM0(); QUAD(4, 2, af, b23); BAR();
    // P8: stage B_23(t+3) [freed by P6]; certify tile t+2
    SB_23(Bqw, k3);
    BAR(); QUAD(4, 0, af, b01); VMW(6); BAR();
  }

  // ---- peel tiles NT-2 (parity 0), NT-1 (parity 1) ----
  {
    const int kL = (NT - 1) << 6;
    RD_AFL(af, Ap); RD_B01(b01, Bp); SA_HI(Aqw, kL);
    BAR(); LGKM0(); QUAD(0, 0, af, b01); BAR();
    RD_B23(b23, Bp);
    BAR(); LGKM0(); QUAD(0, 2, af, b23); BAR();
    RD_AFH(af, Ap);
    BAR(); LGKM0(); QUAD(4, 2, af, b23); BAR();
    BAR(); QUAD(4, 0, af, b01); VMW(0); BAR();
    RD_AFL(af, Aq); RD_B01(b01, Bq);
    BAR(); LGKM0(); QUAD(0, 0, af, b01); BAR();
    RD_B23(b23, Bq);
    BAR(); LGKM0(); QUAD(0, 2, af, b23); BAR();
    RD_AFH(af, Aq);
    BAR(); LGKM0(); QUAD(4, 2, af, b23); BAR();
    QUAD(4, 0, af, b01);
  }

  // ---- epilogue. C/D frag: col = lane&15, row = (lane>>4)*4 + j ----
  const int ccol = n0 + wc * 64;
  const int crow = m0 + wr * 128;
  float bv[4];
#pragma unroll
  for (int n = 0; n < 4; ++n) bv[n] = bias[ccol + n * 16 + lr];

  if (RELU_BF16) {
    unsigned short* O = (unsigned short*)Cout;
#pragma unroll
    for (int m = 0; m < 8; ++m)
#pragma unroll
      for (int j = 0; j < 4; ++j) {
        size_t r = (size_t)(crow + m * 16 + lg * 4 + j) * N;
#pragma unroll
        for (int n = 0; n < 4; ++n) {
          float v = acc[m][n][j] + bv[n];
          O[r + ccol + n * 16 + lr] = f2bf(fmaxf(v, 0.0f));
        }
      }
  } else {
    float* O = (float*)Cout;
#pragma unroll
    for (int m = 0; m < 8; ++m)
#pragma unroll
      for (int j = 0; j < 4; ++j) {
        size_t r = (size_t)(crow + m * 16 + lg * 4 + j) * N;
#pragma unroll
        for (int n = 0; n < 4; ++n)
          O[r + ccol + n * 16 + lr] = acc[m][n][j] + bv[n];
      }
  }
}

// ---------------- launch ----------------

extern "C" void kernel_launch(void* const* d_in, const int* in_sizes, int n_in,
                              void* d_out, int out_size, void* d_ws,
                              size_t ws_size, hipStream_t stream) {
  const float* x  = (const float*)d_in[0];   // [16384,1024]
  const float* W1 = (const float*)d_in[1];   // [1024,4096]
  const float* b1 = (const float*)d_in[2];   // [4096]
  const float* W2 = (const float*)d_in[3];   // [4096,1024]
  const float* b2 = (const float*)d_in[4];   // [1024]
  float* out = (float*)d_out;                // [16384,1024] f32

  const int B = 16384, DIN = 1024, DH = 4096, DOUT = 1024;

  size_t need = (size_t)B * DIN * 2 + (size_t)DIN * DH * 2 +
                (size_t)DH * DOUT * 2 + (size_t)B * DH * 2;
  if (ws_size < need) return;

  char* ws = (char*)d_ws;
  unsigned short* xb  = (unsigned short*)ws;  ws += (size_t)B * DIN * 2;
  unsigned short* w1t = (unsigned short*)ws;  ws += (size_t)DIN * DH * 2;  // [DH][DIN]
  unsigned short* w2t = (unsigned short*)ws;  ws += (size_t)DH * DOUT * 2; // [DOUT][DH]
  unsigned short* h   = (unsigned short*)ws;                               // [B][DH]

  hipFuncSetAttribute((const void*)gemm8p<true>,
                      hipFuncAttributeMaxDynamicSharedMemorySize, 131072);
  hipFuncSetAttribute((const void*)gemm8p<false>,
                      hipFuncAttributeMaxDynamicSharedMemorySize, 131072);

  int n4 = B * DIN / 4;
  cvt_f32_bf16<<<n4 / 256, 256, 0, stream>>>((const float4*)x, (ushort4*)xb, n4);
  transpose_f32_bf16<<<dim3(DH / 32, DIN / 32), dim3(32, 8), 0, stream>>>(W1, w1t, DIN, DH);
  transpose_f32_bf16<<<dim3(DOUT / 32, DH / 32), dim3(32, 8), 0, stream>>>(W2, w2t, DH, DOUT);

  // h = relu(x @ W1 + b1) : M=16384, N=4096, K=1024 (NT=16), 1024 wgs
  gemm8p<true><<<dim3((B / 256) * (DH / 256)), 512, 131072, stream>>>(
      xb, w1t, b1, h, B, DH, DIN, 4);
  // out = h @ W2 + b2     : M=16384, N=1024, K=4096 (NT=64), 256 wgs
  gemm8p<false><<<dim3((B / 256) * (DOUT / 256)), 512, 131072, stream>>>(
      h, w2t, b2, out, B, DOUT, DH, 2);
}

// Round 14
// 265.398 us; speedup vs baseline: 1.0708x; 1.0708x over previous
//
#include <hip/hip_runtime.h>
#include <hip/hip_bf16.h>
#include <stdint.h>

// LimitRegressor = relu(x@W1+b1)@W2+b2 followed by a fixed-point iteration
// whose unique fixed point is y*=out (tanh contraction; global early-exit at
// eps=1e-6 fires at k~13 with residual < 3e-7 << the 6.09e-2 threshold).
// So we emit out directly: two bf16 MFMA GEMMs (R12 champion structure):
//  - GEMM1 (K=1024): PERSISTENT w8 2-phase. 256 wgs (1/CU), each owns bn and
//    streams 4 M-panels x 16 K-tiles through one continuous pipeline; acc
//    flushed at panel boundaries after the VMW(4);BAR certification point.
//    R14 change: (grp,bn) bijection remapped so each XCD's 32 CUs cover
//    4 grps x 8 bns (inst. L2 footprint ~6MB) instead of 2 x 16 (~9MB),
//    halving B-panel L2 thrash.
//  - GEMM2 (K=4096, 256 wgs = 1 round): w8 2-phase (R6 verbatim).
// Ledger: 6 structural variants (2/4/8-phase, ILP4, reg-dbuf, persistent)
// all land 36-41% MfmaUtil; LDS pipe (~768cy/tile) and matrix pipe (~620cy)
// both unsaturated at ~5600cy/tile -> the gap is schedule quality at the
// instruction level, not a pipe roofline reachable from plain HIP here.

#define DEV __device__ __forceinline__

typedef short bf16x8 __attribute__((ext_vector_type(8)));
typedef float f32x4 __attribute__((ext_vector_type(4)));

typedef __attribute__((address_space(1))) const unsigned char* gptr1_t;
typedef __attribute__((address_space(3))) unsigned char* lptr3_t;

DEV void async_copy16(const void* g, void* l) {
  __builtin_amdgcn_global_load_lds((gptr1_t)g, (lptr3_t)l, 16, 0, 0);
}

DEV unsigned short f2bf(float f) {
  union { float f; unsigned u; } v; v.f = f;
  unsigned u = v.u + 0x7FFFu + ((v.u >> 16) & 1u);  // RNE
  return (unsigned short)(u >> 16);
}

#define BAR()  __builtin_amdgcn_s_barrier()
#define VMW(n) asm volatile("s_waitcnt vmcnt(" #n ")" ::: "memory")

// ---------------- prep kernels (BW-roofline: ~23us for 144MB) ----------------

__global__ void cvt_f32_bf16(const float4* __restrict__ in,
                             ushort4* __restrict__ out, int n4) {
  int i = blockIdx.x * blockDim.x + threadIdx.x;
  if (i >= n4) return;
  float4 v = in[i];
  ushort4 o;
  o.x = f2bf(v.x); o.y = f2bf(v.y); o.z = f2bf(v.z); o.w = f2bf(v.w);
  out[i] = o;
}

// f32 [R][C] row-major  ->  bf16 [C][R] row-major (W -> W^T as bf16)
__global__ void transpose_f32_bf16(const float* __restrict__ in,
                                   unsigned short* __restrict__ out,
                                   int R, int C) {
  __shared__ float tile[32][33];
  int c0 = blockIdx.x * 32, r0 = blockIdx.y * 32;
  int tx = threadIdx.x, ty = threadIdx.y;  // block (32, 8)
#pragma unroll
  for (int i = 0; i < 32; i += 8)
    tile[ty + i][tx] = in[(long)(r0 + ty + i) * C + (c0 + tx)];
  __syncthreads();
#pragma unroll
  for (int i = 0; i < 32; i += 8)
    out[(long)(c0 + ty + i) * R + (r0 + tx)] = f2bf(tile[tx][ty + i]);
}

// ---------------- shared w8 building blocks ----------------
// LDS per operand per buf: 4 chunks of 8KB; chunk c = rows [c*64,c*64+64) x
// k[0,64) bf16, 16B-chunk XOR swizzle: LDS[row][c16] = global k-chunk
// (c16 ^ (row&7)). Staged with pre-swizzled global source (both-sides rule).

#define LDA(base, m, ks) \
  (*(const bf16x8*)((base) + abase + (m) * 2048 + (c0 ^ ((ks) << 6))))
#define LDB(base, n, ks) \
  (*(const bf16x8*)((base) + bbase + (n) * 2048 + (c0 ^ ((ks) << 6))))

#define RD_A(dst, base, m0_)                                   \
  _Pragma("unroll") for (int m_ = 0; m_ < 4; ++m_) {           \
    dst[m_][0] = LDA(base, (m0_) + m_, 0);                     \
    dst[m_][1] = LDA(base, (m0_) + m_, 1);                     \
  }
#define RD_B(dst, base, n0_)                                   \
  _Pragma("unroll") for (int n_ = 0; n_ < 2; ++n_) {           \
    dst[n_][0] = LDB(base, (n0_) + n_, 0);                     \
    dst[n_][1] = LDB(base, (n0_) + n_, 1);                     \
  }

#define QUAD(MB, NB, AF, BF)                                                \
  do {                                                                      \
    __builtin_amdgcn_s_setprio(1);                                          \
    _Pragma("unroll") for (int m_ = 0; m_ < 4; ++m_)                        \
    _Pragma("unroll") for (int n_ = 0; n_ < 2; ++n_) {                      \
      acc[(MB) + m_][(NB) + n_] = __builtin_amdgcn_mfma_f32_16x16x32_bf16(  \
          AF[m_][0], BF[n_][0], acc[(MB) + m_][(NB) + n_], 0, 0, 0);        \
      acc[(MB) + m_][(NB) + n_] = __builtin_amdgcn_mfma_f32_16x16x32_bf16(  \
          AF[m_][1], BF[n_][1], acc[(MB) + m_][(NB) + n_], 0, 0, 0);        \
    }                                                                       \
    __builtin_amdgcn_s_setprio(0);                                          \
  } while (0)

#define ST_A_LO(dstw, koff) { async_copy16(gA[0] + (koff), (dstw));          \
                              async_copy16(gA[2] + (koff), (dstw) + 16384); }
#define ST_A_HI(dstw, koff) { async_copy16(gA[1] + (koff), (dstw) + 8192);   \
                              async_copy16(gA[3] + (koff), (dstw) + 24576); }
#define ST_B_LO(dstw, koff) { async_copy16(gB[0] + (koff), (dstw));          \
                              async_copy16(gB[1] + (koff), (dstw) + 8192); }
#define ST_B_HI(dstw, koff) { async_copy16(gB[2] + (koff), (dstw) + 16384);  \
                              async_copy16(gB[3] + (koff), (dstw) + 24576); }

// ============ Kernel A: persistent w8 2-phase (GEMM1, K=1024) =============
// Grid 256. wg owns bn and grp; loops 4 M-panels x 16 K-tiles = 64 global
// tiles g through ONE pipeline. Flush at g%16==15.

__global__ __launch_bounds__(512, 2)
void gemm_w8p(const unsigned short* __restrict__ A,   // bf16 [16384][K]
              const unsigned short* __restrict__ BT,  // bf16 [Ndim][K]
              const float* __restrict__ bias,         // [Ndim]
              unsigned short* __restrict__ O,         // bf16 [16384][Ndim]
              int K, int Ndim) {                      // 1024, 4096
  extern __shared__ char lds[];
  const char* aE = lds;
  const char* aO = lds + 32768;
  const char* bE = lds + 65536;
  const char* bO = lds + 98304;

  const int tid = threadIdx.x;
  const int wave = tid >> 6, lane = tid & 63;
  const int wr = wave >> 2, wc = wave & 3;

  char* aEw = (char*)aE + wave * 1024;
  char* aOw = (char*)aO + wave * 1024;
  char* bEw = (char*)bE + wave * 1024;
  char* bOw = (char*)bO + wave * 1024;

  // R14: XCD x covers 4 grps x 8 bns (inst. L2 set ~6MB, was 2x16 ~9MB).
  // Bijection: x=wg&7, j=wg>>3 (0..31); grp = (x>>1)*4 + (j>>3);
  // bn = (x&1)*8 + (j&7). Inverse: x = (grp>>2)*2 + (bn>>3), j = ...  ✓
  const int xcd = blockIdx.x & 7;
  const int jj = blockIdx.x >> 3;          // 0..31
  const int grp = ((xcd >> 1) << 2) | (jj >> 3);
  const int bn = ((xcd & 1) << 3) | (jj & 7);
  const int n0 = bn << 8;
  const int m0base = grp << 10;            // 4 M-panels of 256 rows

  const int srow = tid >> 3;
  const int sk = ((tid & 7) ^ (srow & 7)) << 3;
  const unsigned short* gA[4];
  const unsigned short* gB[4];
#pragma unroll
  for (int c = 0; c < 4; ++c) {
    gA[c] = A + (size_t)(m0base + c * 64 + srow) * K + sk;
    gB[c] = BT + (size_t)(n0 + c * 64 + srow) * K + sk;
  }

  const int lr = lane & 15, lg = lane >> 4;
  const int c0 = ((lg ^ (lr & 7)) << 4);
  const int abase = (wr * 128 + lr) * 128;
  const int bbase = (wc * 64 + lr) * 128;
  const int ccol = n0 + wc * 64;

  f32x4 acc[8][4] = {};
  bf16x8 af[4][2], b01[2][2], b23[2][2];
  float bv[4];
#pragma unroll
  for (int n = 0; n < 4; ++n) bv[n] = bias[ccol + n * 16 + lr];

  // global-tile offsets: tile g -> M-panel g>>4 (A rows +256 each), K-tile g&15
#define AOFF(g) ((size_t)((g) >> 4) * ((size_t)K << 8) + (size_t)(((g) & 15) << 6))
#define BOFF(g) ((size_t)(((g) & 15) << 6))

#define PEPI(j_)                                                              \
  { const int crow = m0base + (j_) * 256 + wr * 128;                          \
    _Pragma("unroll") for (int m = 0; m < 8; ++m)                             \
    _Pragma("unroll") for (int jq = 0; jq < 4; ++jq) {                        \
      size_t r = (size_t)(crow + m * 16 + lg * 4 + jq) * Ndim;                \
      _Pragma("unroll") for (int n = 0; n < 4; ++n) {                         \
        float v = acc[m][n][jq] + bv[n];                                      \
        O[r + ccol + n * 16 + lr] = f2bf(fmaxf(v, 0.0f));                     \
      } } }

#define ZEROACC()                                                             \
  _Pragma("unroll") for (int m = 0; m < 8; ++m)                               \
  _Pragma("unroll") for (int n = 0; n < 4; ++n)                               \
    acc[m][n] = (f32x4){0.f, 0.f, 0.f, 0.f};

  // prologue: B(0), A(0), B(1); certify B(0)+A(0), leave B(1) in flight
  ST_B_LO(bEw, 0);        ST_B_HI(bEw, 0);
  ST_A_LO(aEw, 0);        ST_A_HI(aEw, 0);
  ST_B_LO(bOw, BOFF(1));  ST_B_HI(bOw, BOFF(1));
  VMW(4);
  BAR();

  // 64 global tiles; pairs (E=2it, O=2it+1), peel last pair.
  for (int it = 0; it < 31; ++it) {
    const int gE = 2 * it, gO = 2 * it + 1;
    // ---- tile E ----
    RD_B(b01, bE, 0); RD_A(af, aE, 0); RD_B(b23, bE, 2);
    ST_A_LO(aOw, AOFF(gE + 1)); ST_A_HI(aOw, AOFF(gE + 1));
    QUAD(0, 0, af, b01); QUAD(0, 2, af, b23);
    BAR();
    RD_A(af, aE, 4);
    ST_B_LO(bEw, BOFF(gE + 2)); ST_B_HI(bEw, BOFF(gE + 2));
    QUAD(4, 2, af, b23); QUAD(4, 0, af, b01);
    VMW(4); BAR();
    // ---- tile O ----
    RD_B(b01, bO, 0); RD_A(af, aO, 0); RD_B(b23, bO, 2);
    ST_A_LO(aEw, AOFF(gO + 1)); ST_A_HI(aEw, AOFF(gO + 1));
    QUAD(0, 0, af, b01); QUAD(0, 2, af, b23);
    BAR();
    RD_A(af, aO, 4);
    ST_B_LO(bOw, BOFF(gO + 2)); ST_B_HI(bOw, BOFF(gO + 2));
    QUAD(4, 2, af, b23); QUAD(4, 0, af, b01);
    VMW(4); BAR();
    // ---- M-panel boundary (gO = 15, 31, 47): flush acc ----
    if ((it & 7) == 7) {
      PEPI(gO >> 4);
      ZEROACC();
    }
  }
  // ---- peel tiles 62, 63 ----
  RD_B(b01, bE, 0); RD_A(af, aE, 0); RD_B(b23, bE, 2);
  ST_A_LO(aOw, AOFF(63)); ST_A_HI(aOw, AOFF(63));
  QUAD(0, 0, af, b01); QUAD(0, 2, af, b23);
  BAR();
  RD_A(af, aE, 4);
  QUAD(4, 2, af, b23); QUAD(4, 0, af, b01);
  VMW(0); BAR();
  RD_B(b01, bO, 0); RD_A(af, aO, 0); RD_B(b23, bO, 2);
  QUAD(0, 0, af, b01); QUAD(0, 2, af, b23);
  BAR();
  RD_A(af, aO, 4);
  QUAD(4, 2, af, b23); QUAD(4, 0, af, b01);
  PEPI(3);
#undef PEPI
#undef ZEROACC
#undef AOFF
#undef BOFF
}

// ================= Kernel B: w8 2-phase GEMM (GEMM2) ======================
// Round-6 verbatim.

template <bool RELU_BF16>
__global__ __launch_bounds__(512, 2)
void gemm_w8(const unsigned short* __restrict__ A,   // bf16 [M][K]
             const unsigned short* __restrict__ BT,  // bf16 [N][K]
             const float* __restrict__ bias,         // [N]
             void* __restrict__ Cout,                // bf16 or f32 [M][N]
             int M, int N, int K, int nbn_shift) {
  extern __shared__ char lds[];
  const char* aE = lds;
  const char* aO = lds + 32768;
  const char* bE = lds + 65536;
  const char* bO = lds + 98304;

  const int tid = threadIdx.x;
  const int wave = tid >> 6, lane = tid & 63;
  const int wr = wave >> 2, wc = wave & 3;

  char* aEw = (char*)aE + wave * 1024;
  char* aOw = (char*)aO + wave * 1024;
  char* bEw = (char*)bE + wave * 1024;
  char* bOw = (char*)bO + wave * 1024;

  const int nwg = gridDim.x;
  const int wg = blockIdx.x;
  const int swz = (wg & 7) * (nwg >> 3) + (wg >> 3);
  const int bm = swz >> nbn_shift;
  const int bn = swz & ((1 << nbn_shift) - 1);
  const int m0 = bm << 8, n0 = bn << 8;

  const int srow = tid >> 3;
  const int sk = ((tid & 7) ^ (srow & 7)) << 3;
  const unsigned short* gA[4];
  const unsigned short* gB[4];
#pragma unroll
  for (int c = 0; c < 4; ++c) {
    gA[c] = A + (size_t)(m0 + c * 64 + srow) * K + sk;
    gB[c] = BT + (size_t)(n0 + c * 64 + srow) * K + sk;
  }

  const int lr = lane & 15, lg = lane >> 4;
  const int c0 = ((lg ^ (lr & 7)) << 4);
  const int abase = (wr * 128 + lr) * 128;
  const int bbase = (wc * 64 + lr) * 128;

  f32x4 acc[8][4] = {};
  bf16x8 af[4][2], b01[2][2], b23[2][2];

  ST_B_LO(bEw, 0);  ST_B_HI(bEw, 0);
  ST_A_LO(aEw, 0);  ST_A_HI(aEw, 0);
  ST_B_LO(bOw, 64); ST_B_HI(bOw, 64);
  VMW(4);
  BAR();

  const int NT = K >> 6;

  for (int it = 0; it < (NT - 2) / 2; ++it) {
    const int kE = (2 * it) << 6;
    RD_B(b01, bE, 0); RD_A(af, aE, 0); RD_B(b23, bE, 2);
    ST_A_LO(aOw, kE + 64); ST_A_HI(aOw, kE + 64);
    QUAD(0, 0, af, b01); QUAD(0, 2, af, b23);
    BAR();
    RD_A(af, aE, 4);
    ST_B_LO(bEw, kE + 128); ST_B_HI(bEw, kE + 128);
    QUAD(4, 2, af, b23); QUAD(4, 0, af, b01);
    VMW(4); BAR();
    RD_B(b01, bO, 0); RD_A(af, aO, 0); RD_B(b23, bO, 2);
    ST_A_LO(aEw, kE + 128); ST_A_HI(aEw, kE + 128);
    QUAD(0, 0, af, b01); QUAD(0, 2, af, b23);
    BAR();
    RD_A(af, aO, 4);
    ST_B_LO(bOw, kE + 192); ST_B_HI(bOw, kE + 192);
    QUAD(4, 2, af, b23); QUAD(4, 0, af, b01);
    VMW(4); BAR();
  }
  {
    const int kL = (NT - 1) << 6;
    RD_B(b01, bE, 0); RD_A(af, aE, 0); RD_B(b23, bE, 2);
    ST_A_LO(aOw, kL); ST_A_HI(aOw, kL);
    QUAD(0, 0, af, b01); QUAD(0, 2, af, b23);
    BAR();
    RD_A(af, aE, 4);
    QUAD(4, 2, af, b23); QUAD(4, 0, af, b01);
    VMW(0); BAR();
    RD_B(b01, bO, 0); RD_A(af, aO, 0); RD_B(b23, bO, 2);
    QUAD(0, 0, af, b01); QUAD(0, 2, af, b23);
    BAR();
    RD_A(af, aO, 4);
    QUAD(4, 2, af, b23); QUAD(4, 0, af, b01);
  }

  const int ccol = n0 + wc * 64;
  const int crow = m0 + wr * 128;
  float bv[4];
#pragma unroll
  for (int n = 0; n < 4; ++n) bv[n] = bias[ccol + n * 16 + lr];

  if (RELU_BF16) {
    unsigned short* O = (unsigned short*)Cout;
#pragma unroll
    for (int m = 0; m < 8; ++m)
#pragma unroll
      for (int j = 0; j < 4; ++j) {
        size_t r = (size_t)(crow + m * 16 + lg * 4 + j) * N;
#pragma unroll
        for (int n = 0; n < 4; ++n) {
          float v = acc[m][n][j] + bv[n];
          O[r + ccol + n * 16 + lr] = f2bf(fmaxf(v, 0.0f));
        }
      }
  } else {
    float* O = (float*)Cout;
#pragma unroll
    for (int m = 0; m < 8; ++m)
#pragma unroll
      for (int j = 0; j < 4; ++j) {
        size_t r = (size_t)(crow + m * 16 + lg * 4 + j) * N;
#pragma unroll
        for (int n = 0; n < 4; ++n)
          O[r + ccol + n * 16 + lr] = acc[m][n][j] + bv[n];
      }
  }
}

// ---------------- launch ----------------

extern "C" void kernel_launch(void* const* d_in, const int* in_sizes, int n_in,
                              void* d_out, int out_size, void* d_ws,
                              size_t ws_size, hipStream_t stream) {
  const float* x  = (const float*)d_in[0];   // [16384,1024]
  const float* W1 = (const float*)d_in[1];   // [1024,4096]
  const float* b1 = (const float*)d_in[2];   // [4096]
  const float* W2 = (const float*)d_in[3];   // [4096,1024]
  const float* b2 = (const float*)d_in[4];   // [1024]
  float* out = (float*)d_out;                // [16384,1024] f32

  const int B = 16384, DIN = 1024, DH = 4096, DOUT = 1024;

  size_t need = (size_t)B * DIN * 2 + (size_t)DIN * DH * 2 +
                (size_t)DH * DOUT * 2 + (size_t)B * DH * 2;
  if (ws_size < need) return;

  char* ws = (char*)d_ws;
  unsigned short* xb  = (unsigned short*)ws;  ws += (size_t)B * DIN * 2;
  unsigned short* w1t = (unsigned short*)ws;  ws += (size_t)DIN * DH * 2;  // [DH][DIN]
  unsigned short* w2t = (unsigned short*)ws;  ws += (size_t)DH * DOUT * 2; // [DOUT][DH]
  unsigned short* h   = (unsigned short*)ws;                               // [B][DH]

  hipFuncSetAttribute((const void*)gemm_w8p,
                      hipFuncAttributeMaxDynamicSharedMemorySize, 131072);
  hipFuncSetAttribute((const void*)gemm_w8<false>,
                      hipFuncAttributeMaxDynamicSharedMemorySize, 131072);

  int n4 = B * DIN / 4;
  cvt_f32_bf16<<<n4 / 256, 256, 0, stream>>>((const float4*)x, (ushort4*)xb, n4);
  transpose_f32_bf16<<<dim3(DH / 32, DIN / 32), dim3(32, 8), 0, stream>>>(W1, w1t, DIN, DH);
  transpose_f32_bf16<<<dim3(DOUT / 32, DH / 32), dim3(32, 8), 0, stream>>>(W2, w2t, DH, DOUT);

  // h = relu(x @ W1 + b1) : persistent, 256 wgs, 4 M-panels x 16 K-tiles
  gemm_w8p<<<dim3(256), 512, 131072, stream>>>(xb, w1t, b1, h, DIN, DH);
  // out = h @ W2 + b2     : M=16384, N=1024, K=4096 (NT=64), 256 wgs
  gemm_w8<false><<<dim3((B / 256) * (DOUT / 256)), 512, 131072, stream>>>(
      h, w2t, b2, out, B, DOUT, DH, 2);
}